// Round 1
// baseline (5751.564 us; speedup 1.0000x reference)
//
#include <hip/hip_runtime.h>
#include <hip/hip_bf16.h>
#include <math.h>

// Problem constants (B,N,D,H,E) = (32,512,512,8,4), HD=64
constexpr int CB = 32, CN = 512, CD = 512, CH = 8, CHD = 64, CE = 4;
constexpr float LN_EPS = 1e-3f;

// ---------------- LayerNorm (optionally + residual), row per block ----------
template<int WIDTH, bool ADDRES>
__global__ void ln_kernel(const float* __restrict__ in, const float* __restrict__ g,
                          const float* __restrict__ be, const float* __restrict__ res,
                          float* __restrict__ out) {
    constexpr int NPT = WIDTH / 256;
    const int row = blockIdx.x;
    const int tid = threadIdx.x;
    const float* p = in + (size_t)row * WIDTH;
    float vals[NPT];
    float s = 0.f;
#pragma unroll
    for (int i = 0; i < NPT; ++i) { vals[i] = p[tid + i * 256]; s += vals[i]; }
    __shared__ float red[6];
#pragma unroll
    for (int off = 32; off > 0; off >>= 1) s += __shfl_down(s, off);
    const int wave = tid >> 6, lane = tid & 63;
    if (lane == 0) red[wave] = s;
    __syncthreads();
    if (tid == 0) red[4] = (red[0] + red[1] + red[2] + red[3]) * (1.0f / WIDTH);
    __syncthreads();
    const float mean = red[4];
    float s2 = 0.f;
#pragma unroll
    for (int i = 0; i < NPT; ++i) { float d = vals[i] - mean; s2 += d * d; }
#pragma unroll
    for (int off = 32; off > 0; off >>= 1) s2 += __shfl_down(s2, off);
    __syncthreads();
    if (lane == 0) red[wave] = s2;
    __syncthreads();
    if (tid == 0) red[5] = rsqrtf((red[0] + red[1] + red[2] + red[3]) * (1.0f / WIDTH) + LN_EPS);
    __syncthreads();
    const float rstd = red[5];
    float* q = out + (size_t)row * WIDTH;
    const float* r = ADDRES ? (res + (size_t)row * WIDTH) : nullptr;
#pragma unroll
    for (int i = 0; i < NPT; ++i) {
        const int c = tid + i * 256;
        float v = (vals[i] - mean) * rstd * g[c] + be[c];
        if (ADDRES) v += r[c];
        q[c] = v;
    }
}

// ---------------- fp32 tiled GEMM: C = A[M,K] @ W[K,Nc] + bias (+gelu)(+res)
// 64x64 tile, BK=16, 256 threads, 4x4 microtile. M,Nc %64==0, K %16==0.
template<bool GELU, bool RES>
__global__ void gemm_kernel(const float* __restrict__ A, const float* __restrict__ W,
                            const float* __restrict__ bias, const float* __restrict__ res,
                            float* __restrict__ C, int M, int Nc, int K) {
    constexpr int BM = 64, BN = 64, BK = 16;
    __shared__ __align__(16) float As[BK][BM];
    __shared__ __align__(16) float Ws[BK][BN];
    const int tid = threadIdx.x;
    const int bx = blockIdx.x;  // N tile
    const int by = blockIdx.y;  // M tile
    const int tx = tid % 16, ty = tid / 16;
    float acc[4][4] = {};
    const int a_row = tid / 4;
    const int a_col4 = (tid % 4) * 4;
    const int w_row = tid / 16;
    const int w_col4 = (tid % 16) * 4;
    const float* Ag = A + (size_t)(by * BM + a_row) * K + a_col4;
    const float* Wg = W + (size_t)w_row * Nc + bx * BN + w_col4;
    for (int k0 = 0; k0 < K; k0 += BK) {
        float4 av = *(const float4*)(Ag + k0);
        float4 wv = *(const float4*)(Wg + (size_t)k0 * Nc);
        As[a_col4 + 0][a_row] = av.x;
        As[a_col4 + 1][a_row] = av.y;
        As[a_col4 + 2][a_row] = av.z;
        As[a_col4 + 3][a_row] = av.w;
        *(float4*)&Ws[w_row][w_col4] = wv;
        __syncthreads();
#pragma unroll
        for (int kk = 0; kk < BK; ++kk) {
            float rm[4], rn[4];
#pragma unroll
            for (int i = 0; i < 4; ++i) rm[i] = As[kk][ty * 4 + i];
#pragma unroll
            for (int j = 0; j < 4; ++j) rn[j] = Ws[kk][tx * 4 + j];
#pragma unroll
            for (int i = 0; i < 4; ++i)
#pragma unroll
                for (int j = 0; j < 4; ++j) acc[i][j] += rm[i] * rn[j];
        }
        __syncthreads();
    }
    const int crow = by * BM + ty * 4;
    const int ccol = bx * BN + tx * 4;
#pragma unroll
    for (int i = 0; i < 4; ++i) {
#pragma unroll
        for (int j = 0; j < 4; ++j) {
            float v = acc[i][j] + bias[ccol + j];
            if (GELU) v = 0.5f * v * (1.0f + erff(v * 0.70710678118654752440f));
            if (RES) v += res[(size_t)(crow + i) * Nc + ccol + j];
            C[(size_t)(crow + i) * Nc + ccol + j] = v;
        }
    }
}

// ---------------- fused attention: one block per (b, n, h); h fastest -------
// qkv layout: [B, N, 3*D] with column = which*512 + h*64 + d
__global__ void attn_kernel(const float* __restrict__ qkv, const float* __restrict__ inter,
                            const int* __restrict__ mask, float* __restrict__ o) {
    const int bid = blockIdx.x;
    const int h = bid % CH;
    const int n = (bid / CH) % CN;
    const int b = bid / (CH * CN);
    const int tid = threadIdx.x;

    __shared__ float qs[CHD];
    __shared__ float sc[CN];
    __shared__ float red[10];
    __shared__ float part[4][CHD];

    const float* qrow = qkv + ((size_t)(b * CN + n)) * (3 * CD) + h * CHD;
    if (tid < CHD) qs[tid] = qrow[tid];
    __syncthreads();

    float scv[2];
#pragma unroll
    for (int c = 0; c < 2; ++c) {
        const int m = tid + c * 256;
        const float* krow = qkv + ((size_t)(b * CN + m)) * (3 * CD) + CD + h * CHD;
        float dot = 0.f;
#pragma unroll
        for (int d = 0; d < CHD; d += 4) {
            float4 kv = *(const float4*)(krow + d);
            dot += qs[d] * kv.x + qs[d + 1] * kv.y + qs[d + 2] * kv.z + qs[d + 3] * kv.w;
        }
        float s = dot * 0.125f + inter[(((size_t)(b * CN + n)) * CN + m) * CH + h];
        if (mask[((size_t)(b * CN + n)) * CN + m] == 0) s += -1e9f;
        scv[c] = s;
    }

    const int wave = tid >> 6, lane = tid & 63;
    // block max
    float mx = fmaxf(scv[0], scv[1]);
#pragma unroll
    for (int off = 32; off > 0; off >>= 1) mx = fmaxf(mx, __shfl_down(mx, off));
    if (lane == 0) red[wave] = mx;
    __syncthreads();
    if (tid == 0) red[8] = fmaxf(fmaxf(red[0], red[1]), fmaxf(red[2], red[3]));
    __syncthreads();
    mx = red[8];
    // block sum of exp
    const float e0 = expf(scv[0] - mx), e1 = expf(scv[1] - mx);
    float sm = e0 + e1;
#pragma unroll
    for (int off = 32; off > 0; off >>= 1) sm += __shfl_down(sm, off);
    if (lane == 0) red[wave] = sm;
    __syncthreads();
    if (tid == 0) red[9] = red[0] + red[1] + red[2] + red[3];
    __syncthreads();
    const float inv = 1.0f / red[9];
    sc[tid] = e0 * inv;
    sc[tid + 256] = e1 * inv;
    __syncthreads();

    // PV: o[d] = sum_m attn[m] * V[m][d]
    const int d = tid & 63;
    const int quarter = tid >> 6;
    const float* vbase = qkv + ((size_t)(b * CN)) * (3 * CD) + 2 * CD + h * CHD + d;
    float accv = 0.f;
    const int m0 = quarter * 128;
    for (int m = m0; m < m0 + 128; ++m) accv += sc[m] * vbase[(size_t)m * (3 * CD)];
    part[quarter][d] = accv;
    __syncthreads();
    if (tid < CHD) {
        float r = part[0][tid] + part[1][tid] + part[2][tid] + part[3][tid];
        o[((size_t)(b * CN + n)) * CD + h * CHD + tid] = r;
    }
}

// ---------------- driver ----------------------------------------------------
extern "C" void kernel_launch(void* const* d_in, const int* in_sizes, int n_in,
                              void* d_out, int out_size, void* d_ws, size_t ws_size,
                              hipStream_t stream) {
    const float* x      = (const float*)d_in[0];
    const int*   mask   = (const int*)d_in[1];
    const float* inter  = (const float*)d_in[2];
    const float* w_qkv  = (const float*)d_in[3];
    const float* b_qkv  = (const float*)d_in[4];
    const float* w_out  = (const float*)d_in[5];
    const float* b_out  = (const float*)d_in[6];
    const float* w1     = (const float*)d_in[7];
    const float* b1     = (const float*)d_in[8];
    const float* w2     = (const float*)d_in[9];
    const float* b2     = (const float*)d_in[10];
    const float* g_pre  = (const float*)d_in[11];
    const float* be_pre = (const float*)d_in[12];
    const float* g_post = (const float*)d_in[13];
    const float* be_post= (const float*)d_in[14];
    const float* g_ffn  = (const float*)d_in[15];
    const float* be_ffn = (const float*)d_in[16];
    const float* g_mid  = (const float*)d_in[17];
    const float* be_mid = (const float*)d_in[18];
    float* out = (float*)d_out;

    char* ws = (char*)d_ws;
    const size_t rows = (size_t)CB * CN;                 // 16384
    const size_t szD  = rows * CD * sizeof(float);       // 33,554,432
    // layout: [R0: h/o2/f (szD)] [R3: attended (szD)] [RBIG: qkv+o | f1 (4*szD)]
    float* ws_h   = (float*)(ws);
    float* ws_att = (float*)(ws + szD);
    float* ws_qkv = (float*)(ws + 2 * szD);              // rows*1536
    float* ws_o   = (float*)(ws + 2 * szD + 3 * szD);    // rows*512 (after qkv)
    float* ws_f1  = (float*)(ws + 2 * szD);              // rows*2048 (reuses qkv+o)

    const int M = (int)rows;

    // 1. h = LN(x)
    ln_kernel<512, false><<<M, 256, 0, stream>>>(x, g_pre, be_pre, nullptr, ws_h);
    // 2. qkv = h @ w_qkv + b_qkv
    gemm_kernel<false, false><<<dim3(1536 / 64, M / 64), 256, 0, stream>>>(
        ws_h, w_qkv, b_qkv, nullptr, ws_qkv, M, 1536, 512);
    // 3. attention -> o (already in [B,N,D] head-merged layout)
    attn_kernel<<<CB * CN * CH, 256, 0, stream>>>(ws_qkv, inter, mask, ws_o);
    // 4. o2 = o @ w_out + b_out   (into R0; h is dead)
    gemm_kernel<false, false><<<dim3(512 / 64, M / 64), 256, 0, stream>>>(
        ws_o, w_out, b_out, nullptr, ws_h, M, 512, 512);
    // 5. attended = LN(o2) + x
    ln_kernel<512, true><<<M, 256, 0, stream>>>(ws_h, g_post, be_post, x, ws_att);
    // 6. f = LN(attended)  (into R0; o2 dead)
    ln_kernel<512, false><<<M, 256, 0, stream>>>(ws_att, g_ffn, be_ffn, nullptr, ws_h);
    // 7. f1 = gelu(f @ w1 + b1)   (RBIG; qkv/o dead)
    gemm_kernel<true, false><<<dim3(2048 / 64, M / 64), 256, 0, stream>>>(
        ws_h, w1, b1, nullptr, ws_f1, M, 2048, 512);
    // 8. f1 = LN(f1) in-place (mid LN)
    ln_kernel<2048, false><<<M, 256, 0, stream>>>(ws_f1, g_mid, be_mid, nullptr, ws_f1);
    // 9. out = f1 @ w2 + b2 + attended
    gemm_kernel<false, true><<<dim3(512 / 64, M / 64), 256, 0, stream>>>(
        ws_f1, w2, b2, ws_att, out, M, 512, 2048);
}

// Round 2
// 2004.077 us; speedup vs baseline: 2.8699x; 2.8699x over previous
//
#include <hip/hip_runtime.h>
#include <hip/hip_bf16.h>
#include <math.h>

// Problem constants (B,N,D,H,E) = (32,512,512,8,4), HD=64
constexpr int CB = 32, CN = 512, CD = 512, CH = 8, CHD = 64, CE = 4;
constexpr float LN_EPS = 1e-3f;

// ---------------- LayerNorm (optionally + residual), row per block ----------
template<int WIDTH, bool ADDRES>
__global__ void ln_kernel(const float* __restrict__ in, const float* __restrict__ g,
                          const float* __restrict__ be, const float* __restrict__ res,
                          float* __restrict__ out) {
    constexpr int NPT = WIDTH / 256;
    const int row = blockIdx.x;
    const int tid = threadIdx.x;
    const float* p = in + (size_t)row * WIDTH;
    float vals[NPT];
    float s = 0.f;
#pragma unroll
    for (int i = 0; i < NPT; ++i) { vals[i] = p[tid + i * 256]; s += vals[i]; }
    __shared__ float red[6];
#pragma unroll
    for (int off = 32; off > 0; off >>= 1) s += __shfl_down(s, off);
    const int wave = tid >> 6, lane = tid & 63;
    if (lane == 0) red[wave] = s;
    __syncthreads();
    if (tid == 0) red[4] = (red[0] + red[1] + red[2] + red[3]) * (1.0f / WIDTH);
    __syncthreads();
    const float mean = red[4];
    float s2 = 0.f;
#pragma unroll
    for (int i = 0; i < NPT; ++i) { float d = vals[i] - mean; s2 += d * d; }
#pragma unroll
    for (int off = 32; off > 0; off >>= 1) s2 += __shfl_down(s2, off);
    __syncthreads();
    if (lane == 0) red[wave] = s2;
    __syncthreads();
    if (tid == 0) red[5] = rsqrtf((red[0] + red[1] + red[2] + red[3]) * (1.0f / WIDTH) + LN_EPS);
    __syncthreads();
    const float rstd = red[5];
    float* q = out + (size_t)row * WIDTH;
    const float* r = ADDRES ? (res + (size_t)row * WIDTH) : nullptr;
#pragma unroll
    for (int i = 0; i < NPT; ++i) {
        const int c = tid + i * 256;
        float v = (vals[i] - mean) * rstd * g[c] + be[c];
        if (ADDRES) v += r[c];
        q[c] = v;
    }
}

// ---------------- fp32 tiled GEMM: C = A[M,K] @ W[K,Nc] + bias (+gelu)(+res)
template<bool GELU, bool RES>
__global__ void gemm_kernel(const float* __restrict__ A, const float* __restrict__ W,
                            const float* __restrict__ bias, const float* __restrict__ res,
                            float* __restrict__ C, int M, int Nc, int K) {
    constexpr int BM = 64, BN = 64, BK = 16;
    __shared__ __align__(16) float As[BK][BM];
    __shared__ __align__(16) float Ws[BK][BN];
    const int tid = threadIdx.x;
    const int bx = blockIdx.x;  // N tile
    const int by = blockIdx.y;  // M tile
    const int tx = tid % 16, ty = tid / 16;
    float acc[4][4] = {};
    const int a_row = tid / 4;
    const int a_col4 = (tid % 4) * 4;
    const int w_row = tid / 16;
    const int w_col4 = (tid % 16) * 4;
    const float* Ag = A + (size_t)(by * BM + a_row) * K + a_col4;
    const float* Wg = W + (size_t)w_row * Nc + bx * BN + w_col4;
    for (int k0 = 0; k0 < K; k0 += BK) {
        float4 av = *(const float4*)(Ag + k0);
        float4 wv = *(const float4*)(Wg + (size_t)k0 * Nc);
        As[a_col4 + 0][a_row] = av.x;
        As[a_col4 + 1][a_row] = av.y;
        As[a_col4 + 2][a_row] = av.z;
        As[a_col4 + 3][a_row] = av.w;
        *(float4*)&Ws[w_row][w_col4] = wv;
        __syncthreads();
#pragma unroll
        for (int kk = 0; kk < BK; ++kk) {
            float rm[4], rn[4];
#pragma unroll
            for (int i = 0; i < 4; ++i) rm[i] = As[kk][ty * 4 + i];
#pragma unroll
            for (int j = 0; j < 4; ++j) rn[j] = Ws[kk][tx * 4 + j];
#pragma unroll
            for (int i = 0; i < 4; ++i)
#pragma unroll
                for (int j = 0; j < 4; ++j) acc[i][j] += rm[i] * rn[j];
        }
        __syncthreads();
    }
    const int crow = by * BM + ty * 4;
    const int ccol = bx * BN + tx * 4;
#pragma unroll
    for (int i = 0; i < 4; ++i) {
#pragma unroll
        for (int j = 0; j < 4; ++j) {
            float v = acc[i][j] + bias[ccol + j];
            if (GELU) v = 0.5f * v * (1.0f + erff(v * 0.70710678118654752440f));
            if (RES) v += res[(size_t)(crow + i) * Nc + ccol + j];
            C[(size_t)(crow + i) * Nc + ccol + j] = v;
        }
    }
}

// ---------------- tiled flash attention ------------------------------------
// One block per (b, h, q-tile of 64). 256 threads, 4x4 microtiles.
// qkv layout: [B, N, 3*D], column = which*512 + h*64 + d
__global__ __launch_bounds__(256) void attn_kernel(
        const float* __restrict__ qkv, const float* __restrict__ inter,
        const int* __restrict__ mask, float* __restrict__ o) {
    constexpr int QT = 64, MT = 64;
    const int bid = blockIdx.x;
    const int h  = bid % CH;
    const int qt = (bid / CH) % (CN / QT);
    const int b  = bid / (CH * (CN / QT));
    const int tid = threadIdx.x;
    const int tx = tid % 16, ty = tid / 16;

    __shared__ __align__(16) float Qs[CHD][QT];      // [d][q] transposed, 16KB
    __shared__ __align__(16) float Ks[CHD][MT];      // [d][m] transposed, 16KB
    __shared__ __align__(16) float Vs[MT][CHD];      // [m][d] natural,    16KB
    __shared__ __align__(16) float Ps[QT][MT + 4];   // [q][m] padded,   17.4KB

    // ---- stage Q (scaled by 1/sqrt(HD)), transposed into Qs ----
    {
        const int q = tid / 4;              // 0..63
        const int d0 = (tid % 4) * 4;       // 0,4,8,12
        const float* qrow = qkv + ((size_t)(b * CN + qt * QT + q)) * (3 * CD) + h * CHD;
#pragma unroll
        for (int pass = 0; pass < 4; ++pass) {
            const int d = d0 + pass * 16;
            float4 v = *(const float4*)(qrow + d);
            Qs[d + 0][q] = v.x * 0.125f;
            Qs[d + 1][q] = v.y * 0.125f;
            Qs[d + 2][q] = v.z * 0.125f;
            Qs[d + 3][q] = v.w * 0.125f;
        }
    }

    float o_acc[4][4] = {};
    float m_run[4] = {-3.0e38f, -3.0e38f, -3.0e38f, -3.0e38f};
    float l_run[4] = {};

    const int r0 = qt * QT + ty * 4;        // first of this thread's 4 query rows
    const float* interRow[4];
    const int* maskRow[4];
#pragma unroll
    for (int i = 0; i < 4; ++i) {
        interRow[i] = inter + (((size_t)(b * CN + r0 + i)) * CN) * CH + h;
        maskRow[i]  = mask + ((size_t)(b * CN + r0 + i)) * CN;
    }

    for (int mt = 0; mt < CN / MT; ++mt) {
        __syncthreads();   // prior tile's reads of Ks/Vs/Ps complete
        // ---- stage K (transposed) and V (natural) ----
        {
            const int m = tid / 4;
            const int d0 = (tid % 4) * 4;
            const float* krow = qkv + ((size_t)(b * CN + mt * MT + m)) * (3 * CD) + CD + h * CHD;
            const float* vrow = krow + CD;
#pragma unroll
            for (int pass = 0; pass < 4; ++pass) {
                const int d = d0 + pass * 16;
                float4 kv = *(const float4*)(krow + d);
                Ks[d + 0][m] = kv.x;
                Ks[d + 1][m] = kv.y;
                Ks[d + 2][m] = kv.z;
                Ks[d + 3][m] = kv.w;
                *(float4*)&Vs[m][d] = *(const float4*)(vrow + d);
            }
        }
        // ---- prefetch interaction + mask for this tile (16 vals each) ----
        const int m0 = mt * MT + tx * 4;
        float iv[4][4];
        int mv[4][4];
#pragma unroll
        for (int i = 0; i < 4; ++i) {
            const int4 mi = *(const int4*)(maskRow[i] + m0);
            mv[i][0] = mi.x; mv[i][1] = mi.y; mv[i][2] = mi.z; mv[i][3] = mi.w;
#pragma unroll
            for (int j = 0; j < 4; ++j) iv[i][j] = interRow[i][(size_t)(m0 + j) * CH];
        }
        __syncthreads();   // staging visible

        // ---- S = Q @ K^T (64x64x64) ----
        float sv[4][4] = {};
#pragma unroll
        for (int kk = 0; kk < CHD; ++kk) {
            const float4 qv = *(const float4*)&Qs[kk][ty * 4];
            const float4 kv = *(const float4*)&Ks[kk][tx * 4];
            const float qa[4] = {qv.x, qv.y, qv.z, qv.w};
            const float ka[4] = {kv.x, kv.y, kv.z, kv.w};
#pragma unroll
            for (int i = 0; i < 4; ++i)
#pragma unroll
                for (int j = 0; j < 4; ++j) sv[i][j] += qa[i] * ka[j];
        }
        // ---- bias + mask + online softmax ----
#pragma unroll
        for (int i = 0; i < 4; ++i) {
#pragma unroll
            for (int j = 0; j < 4; ++j) {
                float s = sv[i][j] + iv[i][j];
                if (mv[i][j] == 0) s -= 1e9f;
                sv[i][j] = s;
            }
            float rmax = fmaxf(fmaxf(sv[i][0], sv[i][1]), fmaxf(sv[i][2], sv[i][3]));
#pragma unroll
            for (int off = 1; off < 16; off <<= 1) rmax = fmaxf(rmax, __shfl_xor(rmax, off));
            const float nm = fmaxf(m_run[i], rmax);
            const float fac = __expf(m_run[i] - nm);
            m_run[i] = nm;
            float ps = 0.f;
#pragma unroll
            for (int j = 0; j < 4; ++j) { float p = __expf(sv[i][j] - nm); sv[i][j] = p; ps += p; }
#pragma unroll
            for (int off = 1; off < 16; off <<= 1) ps += __shfl_xor(ps, off);
            l_run[i] = l_run[i] * fac + ps;
#pragma unroll
            for (int j = 0; j < 4; ++j) o_acc[i][j] *= fac;
            *(float4*)&Ps[ty * 4 + i][tx * 4] = make_float4(sv[i][0], sv[i][1], sv[i][2], sv[i][3]);
        }
        __syncthreads();   // Ps visible

        // ---- O += P @ V (64x64x64) ----
#pragma unroll 4
        for (int kk = 0; kk < MT; kk += 4) {
            float4 pm[4];
#pragma unroll
            for (int i = 0; i < 4; ++i) pm[i] = *(const float4*)&Ps[ty * 4 + i][kk];
#pragma unroll
            for (int t = 0; t < 4; ++t) {
                const float4 vv = *(const float4*)&Vs[kk + t][tx * 4];
                const float va[4] = {vv.x, vv.y, vv.z, vv.w};
                const float pa[4] = {pm[0].x, pm[1].x, pm[2].x, pm[3].x};
                const float pb[4] = {pm[0].y, pm[1].y, pm[2].y, pm[3].y};
                const float pc[4] = {pm[0].z, pm[1].z, pm[2].z, pm[3].z};
                const float pd[4] = {pm[0].w, pm[1].w, pm[2].w, pm[3].w};
                const float* psel = (t == 0) ? pa : (t == 1) ? pb : (t == 2) ? pc : pd;
#pragma unroll
                for (int i = 0; i < 4; ++i)
#pragma unroll
                    for (int j = 0; j < 4; ++j) o_acc[i][j] += psel[i] * va[j];
            }
        }
    }

    // ---- epilogue: normalize and store ----
#pragma unroll
    for (int i = 0; i < 4; ++i) {
        const float inv = 1.0f / l_run[i];
        float4 ov = make_float4(o_acc[i][0] * inv, o_acc[i][1] * inv,
                                o_acc[i][2] * inv, o_acc[i][3] * inv);
        *(float4*)&o[((size_t)(b * CN + r0 + i)) * CD + h * CHD + tx * 4] = ov;
    }
}

// ---------------- driver ----------------------------------------------------
extern "C" void kernel_launch(void* const* d_in, const int* in_sizes, int n_in,
                              void* d_out, int out_size, void* d_ws, size_t ws_size,
                              hipStream_t stream) {
    const float* x      = (const float*)d_in[0];
    const int*   mask   = (const int*)d_in[1];
    const float* inter  = (const float*)d_in[2];
    const float* w_qkv  = (const float*)d_in[3];
    const float* b_qkv  = (const float*)d_in[4];
    const float* w_out  = (const float*)d_in[5];
    const float* b_out  = (const float*)d_in[6];
    const float* w1     = (const float*)d_in[7];
    const float* b1     = (const float*)d_in[8];
    const float* w2     = (const float*)d_in[9];
    const float* b2     = (const float*)d_in[10];
    const float* g_pre  = (const float*)d_in[11];
    const float* be_pre = (const float*)d_in[12];
    const float* g_post = (const float*)d_in[13];
    const float* be_post= (const float*)d_in[14];
    const float* g_ffn  = (const float*)d_in[15];
    const float* be_ffn = (const float*)d_in[16];
    const float* g_mid  = (const float*)d_in[17];
    const float* be_mid = (const float*)d_in[18];
    float* out = (float*)d_out;

    char* ws = (char*)d_ws;
    const size_t rows = (size_t)CB * CN;                 // 16384
    const size_t szD  = rows * CD * sizeof(float);       // 33,554,432
    float* ws_h   = (float*)(ws);
    float* ws_att = (float*)(ws + szD);
    float* ws_qkv = (float*)(ws + 2 * szD);              // rows*1536
    float* ws_o   = (float*)(ws + 2 * szD + 3 * szD);    // rows*512 (after qkv)
    float* ws_f1  = (float*)(ws + 2 * szD);              // rows*2048 (reuses qkv+o)

    const int M = (int)rows;

    // 1. h = LN(x)
    ln_kernel<512, false><<<M, 256, 0, stream>>>(x, g_pre, be_pre, nullptr, ws_h);
    // 2. qkv = h @ w_qkv + b_qkv
    gemm_kernel<false, false><<<dim3(1536 / 64, M / 64), 256, 0, stream>>>(
        ws_h, w_qkv, b_qkv, nullptr, ws_qkv, M, 1536, 512);
    // 3. tiled flash attention -> o
    attn_kernel<<<CB * (CN / 64) * CH, 256, 0, stream>>>(ws_qkv, inter, mask, ws_o);
    // 4. o2 = o @ w_out + b_out
    gemm_kernel<false, false><<<dim3(512 / 64, M / 64), 256, 0, stream>>>(
        ws_o, w_out, b_out, nullptr, ws_h, M, 512, 512);
    // 5. attended = LN(o2) + x
    ln_kernel<512, true><<<M, 256, 0, stream>>>(ws_h, g_post, be_post, x, ws_att);
    // 6. f = LN(attended)
    ln_kernel<512, false><<<M, 256, 0, stream>>>(ws_att, g_ffn, be_ffn, nullptr, ws_h);
    // 7. f1 = gelu(f @ w1 + b1)
    gemm_kernel<true, false><<<dim3(2048 / 64, M / 64), 256, 0, stream>>>(
        ws_h, w1, b1, nullptr, ws_f1, M, 2048, 512);
    // 8. f1 = LN(f1) in-place (mid LN)
    ln_kernel<2048, false><<<M, 256, 0, stream>>>(ws_f1, g_mid, be_mid, nullptr, ws_f1);
    // 9. out = f1 @ w2 + b2 + attended
    gemm_kernel<false, true><<<dim3(512 / 64, M / 64), 256, 0, stream>>>(
        ws_f1, w2, b2, ws_att, out, M, 512, 2048);
}

// Round 3
// 686.534 us; speedup vs baseline: 8.3777x; 2.9191x over previous
//
#include <hip/hip_runtime.h>
#include <hip/hip_bf16.h>
#include <math.h>

// Problem constants (B,N,D,H,E) = (32,512,512,8,4), HD=64
constexpr int CB = 32, CN = 512, CD = 512, CH = 8, CHD = 64;
constexpr float LN_EPS = 1e-3f;

typedef _Float16 half8 __attribute__((ext_vector_type(8)));
typedef _Float16 half4v __attribute__((ext_vector_type(4)));
typedef float f32x4 __attribute__((ext_vector_type(4)));

__device__ __forceinline__ void async16(const void* g, void* l) {
    __builtin_amdgcn_global_load_lds((const __attribute__((address_space(1))) void*)g,
                                     (__attribute__((address_space(3))) void*)l, 16, 0, 0);
}

// ---------------- weight transpose + fp32->f16: in[K][N] -> out[N][K] ------
__global__ __launch_bounds__(256) void transpose_f16(const float* __restrict__ in,
                                                     _Float16* __restrict__ out,
                                                     int K, int N) {
    __shared__ float t[32][33];
    const int tx = threadIdx.x % 32, ty = threadIdx.x / 32;  // 8 rows per pass
    const int n0 = blockIdx.x * 32, k0 = blockIdx.y * 32;
#pragma unroll
    for (int i = 0; i < 4; ++i)
        t[ty + i * 8][tx] = in[(size_t)(k0 + ty + i * 8) * N + n0 + tx];
    __syncthreads();
#pragma unroll
    for (int i = 0; i < 4; ++i)
        out[(size_t)(n0 + ty + i * 8) * K + k0 + tx] = (_Float16)t[tx][ty + i * 8];
}

// ---------------- LayerNorm, wave per row -----------------------------------
// in: fp32 or f16; out: fp32 or f16; optional fp32 residual added after LN.
template<int WIDTH, bool IN_F16, bool OUT_F16, bool ADDRES>
__global__ __launch_bounds__(256) void ln2_kernel(const void* __restrict__ in_,
        const float* __restrict__ g, const float* __restrict__ be,
        const float* __restrict__ res, void* __restrict__ out_) {
    constexpr int NPL = WIDTH / 64;
    const int row = blockIdx.x * 4 + (threadIdx.x >> 6);
    const int lane = threadIdx.x & 63;
    const int c0 = lane * NPL;
    float v[NPL];
    if (IN_F16) {
        const _Float16* p = (const _Float16*)in_ + (size_t)row * WIDTH + c0;
#pragma unroll
        for (int i = 0; i < NPL / 8; ++i) {
            half8 u = *(const half8*)(p + i * 8);
#pragma unroll
            for (int j = 0; j < 8; ++j) v[i * 8 + j] = (float)u[j];
        }
    } else {
        const float* p = (const float*)in_ + (size_t)row * WIDTH + c0;
#pragma unroll
        for (int i = 0; i < NPL / 4; ++i) {
            float4 u = *(const float4*)(p + i * 4);
            v[i * 4 + 0] = u.x; v[i * 4 + 1] = u.y; v[i * 4 + 2] = u.z; v[i * 4 + 3] = u.w;
        }
    }
    float s1 = 0.f, s2 = 0.f;
#pragma unroll
    for (int i = 0; i < NPL; ++i) { s1 += v[i]; s2 += v[i] * v[i]; }
#pragma unroll
    for (int off = 1; off < 64; off <<= 1) { s1 += __shfl_xor(s1, off); s2 += __shfl_xor(s2, off); }
    const float mean = s1 * (1.0f / WIDTH);
    const float var = s2 * (1.0f / WIDTH) - mean * mean;
    const float rstd = rsqrtf(var + LN_EPS);

    float ov[NPL];
#pragma unroll
    for (int i = 0; i < NPL / 4; ++i) {
        float4 gv = *(const float4*)(g + c0 + i * 4);
        float4 bv = *(const float4*)(be + c0 + i * 4);
        ov[i * 4 + 0] = (v[i * 4 + 0] - mean) * rstd * gv.x + bv.x;
        ov[i * 4 + 1] = (v[i * 4 + 1] - mean) * rstd * gv.y + bv.y;
        ov[i * 4 + 2] = (v[i * 4 + 2] - mean) * rstd * gv.z + bv.z;
        ov[i * 4 + 3] = (v[i * 4 + 3] - mean) * rstd * gv.w + bv.w;
    }
    if (ADDRES) {
        const float* rp = res + (size_t)row * WIDTH + c0;
#pragma unroll
        for (int i = 0; i < NPL / 4; ++i) {
            float4 rv = *(const float4*)(rp + i * 4);
            ov[i * 4 + 0] += rv.x; ov[i * 4 + 1] += rv.y; ov[i * 4 + 2] += rv.z; ov[i * 4 + 3] += rv.w;
        }
    }
    if (OUT_F16) {
        _Float16* po = (_Float16*)out_ + (size_t)row * WIDTH + c0;
#pragma unroll
        for (int i = 0; i < NPL / 8; ++i) {
            half8 hv;
#pragma unroll
            for (int j = 0; j < 8; ++j) hv[j] = (_Float16)ov[i * 8 + j];
            *(half8*)(po + i * 8) = hv;
        }
    } else {
        float* po = (float*)out_ + (size_t)row * WIDTH + c0;
#pragma unroll
        for (int i = 0; i < NPL / 4; ++i) {
            float4 w = make_float4(ov[i * 4 + 0], ov[i * 4 + 1], ov[i * 4 + 2], ov[i * 4 + 3]);
            *(float4*)(po + i * 4) = w;
        }
    }
}

// ---------------- f16 MFMA GEMM: C = A[M,K] @ Wt[N,K]^T + bias --------------
// 128x128 tile, BK=64, 256 thr (4 waves, 2x2), 4x4 frags of 16x16x32 per wave.
// LDS XOR-swizzle: row's 16B-chunk c stored at slot c^(row&7); linear LDS dest
// via global_load_lds with pre-swizzled global source.
template<bool GELU, bool RES, bool OUT_F16>
__global__ __launch_bounds__(256) void gemm_f16(const _Float16* __restrict__ A,
        const _Float16* __restrict__ Wt, const float* __restrict__ bias,
        const float* __restrict__ res, void* __restrict__ Cout,
        int M, int N, int K) {
    __shared__ __align__(16) char As[16384];
    __shared__ __align__(16) char Bs[16384];
    const int tid = threadIdx.x;
    const int nbx = N >> 7;
    const int nwg = (M >> 7) * nbx;
    int gb = blockIdx.x;
    gb = (gb & 7) * (nwg >> 3) + (gb >> 3);   // XCD swizzle (nwg % 8 == 0)
    const int by = gb / nbx, bx = gb % nbx;

    const int lane = tid & 63;
    const int wv = tid >> 6;
    // staging: wave covers 8 rows per call; lane -> (row=lane/8, slot=lane%7)
    const int rsub = lane >> 3;              // 0..7  (== row & 7)
    const int slot = lane & 7;
    const int chunk = slot ^ rsub;           // global 16B k-chunk at this slot
    const _Float16* Abase = A + (size_t)(by * 128) * K + chunk * 8;
    const _Float16* Bbase = Wt + (size_t)(bx * 128) * K + chunk * 8;

    // compute-phase coords
    const int wm = wv >> 1, wn = wv & 1;
    const int lrow = lane & 15;
    const int lk = lane >> 4;
    const int xorv = lane & 7;
    const int aRowB = (wm * 64 + lrow) * 128;
    const int bRowB = (wn * 64 + lrow) * 128;

    f32x4 acc[4][4] = {};

    for (int k0 = 0; k0 < K; k0 += 64) {
#pragma unroll
        for (int t = 0; t < 4; ++t) {
            const int rowb = t * 32 + wv * 8;
            async16(Abase + (size_t)(rowb + rsub) * K + k0, As + rowb * 128);
            async16(Bbase + (size_t)(rowb + rsub) * K + k0, Bs + rowb * 128);
        }
        __syncthreads();
#pragma unroll
        for (int kk = 0; kk < 2; ++kk) {
            const int sa = ((kk * 4 + lk) ^ xorv) << 4;
            half8 af[4], bf[4];
#pragma unroll
            for (int mi = 0; mi < 4; ++mi) af[mi] = *(const half8*)(As + aRowB + mi * 2048 + sa);
#pragma unroll
            for (int ni = 0; ni < 4; ++ni) bf[ni] = *(const half8*)(Bs + bRowB + ni * 2048 + sa);
#pragma unroll
            for (int mi = 0; mi < 4; ++mi)
#pragma unroll
                for (int ni = 0; ni < 4; ++ni)
                    acc[mi][ni] = __builtin_amdgcn_mfma_f32_16x16x32_f16(af[mi], bf[ni], acc[mi][ni], 0, 0, 0);
        }
        __syncthreads();
    }

    // epilogue: D[row=(lane>>4)*4+r][col=lane&15]
    const int lr4 = (lane >> 4) * 4;
    const int lc = lane & 15;
#pragma unroll
    for (int ni = 0; ni < 4; ++ni) {
        const int colg = bx * 128 + wn * 64 + ni * 16 + lc;
        const float bv = bias[colg];
#pragma unroll
        for (int mi = 0; mi < 4; ++mi) {
            const int rowg = by * 128 + wm * 64 + mi * 16 + lr4;
#pragma unroll
            for (int r = 0; r < 4; ++r) {
                float v = acc[mi][ni][r] + bv;
                if (GELU) v = 0.5f * v * (1.0f + erff(v * 0.70710678118654752440f));
                if (RES) v += res[(size_t)(rowg + r) * N + colg];
                if (OUT_F16) ((_Float16*)Cout)[(size_t)(rowg + r) * N + colg] = (_Float16)v;
                else ((float*)Cout)[(size_t)(rowg + r) * N + colg] = v;
            }
        }
    }
}

// ---------------- tiled flash attention (f16 qkv in, f16 o out) -------------
// One block per (b, h, q-tile of 64). qkv: [B,N,1536], col = which*512+h*64+d
__global__ __launch_bounds__(256) void attn_kernel(
        const _Float16* __restrict__ qkv, const float* __restrict__ inter,
        const int* __restrict__ mask, _Float16* __restrict__ o) {
    constexpr int QT = 64, MT = 64;
    const int bid = blockIdx.x;
    const int h  = bid % CH;
    const int qt = (bid / CH) % (CN / QT);
    const int b  = bid / (CH * (CN / QT));
    const int tid = threadIdx.x;
    const int tx = tid % 16, ty = tid / 16;

    __shared__ __align__(16) float Qs[CHD][QT];
    __shared__ __align__(16) float Ks[CHD][MT];
    __shared__ __align__(16) float Vs[MT][CHD];
    __shared__ __align__(16) float Ps[QT][MT + 4];

    {   // stage Q (scaled), transposed
        const int q = tid / 4;
        const int d0 = (tid % 4) * 8;
        const _Float16* qrow = qkv + (size_t)(b * CN + qt * QT + q) * (3 * CD) + h * CHD;
#pragma unroll
        for (int pass = 0; pass < 2; ++pass) {
            const int d = d0 + pass * 32;
            half8 u = *(const half8*)(qrow + d);
#pragma unroll
            for (int j = 0; j < 8; ++j) Qs[d + j][q] = (float)u[j] * 0.125f;
        }
    }

    float o_acc[4][4] = {};
    float m_run[4] = {-3.0e38f, -3.0e38f, -3.0e38f, -3.0e38f};
    float l_run[4] = {};

    const int r0 = qt * QT + ty * 4;
    const float* interRow[4];
    const int* maskRow[4];
#pragma unroll
    for (int i = 0; i < 4; ++i) {
        interRow[i] = inter + (((size_t)(b * CN + r0 + i)) * CN) * CH + h;
        maskRow[i]  = mask + ((size_t)(b * CN + r0 + i)) * CN;
    }

    for (int mt = 0; mt < CN / MT; ++mt) {
        __syncthreads();
        {   // stage K (transposed) + V (natural)
            const int m = tid / 4;
            const int d0 = (tid % 4) * 8;
            const _Float16* krow = qkv + (size_t)(b * CN + mt * MT + m) * (3 * CD) + CD + h * CHD;
            const _Float16* vrow = krow + CD;
#pragma unroll
            for (int pass = 0; pass < 2; ++pass) {
                const int d = d0 + pass * 32;
                half8 ku = *(const half8*)(krow + d);
                half8 vu = *(const half8*)(vrow + d);
#pragma unroll
                for (int j = 0; j < 8; ++j) { Ks[d + j][m] = (float)ku[j]; Vs[m][d + j] = (float)vu[j]; }
            }
        }
        const int m0 = mt * MT + tx * 4;
        float iv[4][4];
        int mv[4][4];
#pragma unroll
        for (int i = 0; i < 4; ++i) {
            const int4 mi_ = *(const int4*)(maskRow[i] + m0);
            mv[i][0] = mi_.x; mv[i][1] = mi_.y; mv[i][2] = mi_.z; mv[i][3] = mi_.w;
#pragma unroll
            for (int j = 0; j < 4; ++j) iv[i][j] = interRow[i][(size_t)(m0 + j) * CH];
        }
        __syncthreads();

        float sv[4][4] = {};
#pragma unroll
        for (int kk = 0; kk < CHD; ++kk) {
            const float4 qv = *(const float4*)&Qs[kk][ty * 4];
            const float4 kv = *(const float4*)&Ks[kk][tx * 4];
            const float qa[4] = {qv.x, qv.y, qv.z, qv.w};
            const float ka[4] = {kv.x, kv.y, kv.z, kv.w};
#pragma unroll
            for (int i = 0; i < 4; ++i)
#pragma unroll
                for (int j = 0; j < 4; ++j) sv[i][j] += qa[i] * ka[j];
        }
#pragma unroll
        for (int i = 0; i < 4; ++i) {
#pragma unroll
            for (int j = 0; j < 4; ++j) {
                float s = sv[i][j] + iv[i][j];
                if (mv[i][j] == 0) s -= 1e9f;
                sv[i][j] = s;
            }
            float rmax = fmaxf(fmaxf(sv[i][0], sv[i][1]), fmaxf(sv[i][2], sv[i][3]));
#pragma unroll
            for (int off = 1; off < 16; off <<= 1) rmax = fmaxf(rmax, __shfl_xor(rmax, off));
            const float nm = fmaxf(m_run[i], rmax);
            const float fac = __expf(m_run[i] - nm);
            m_run[i] = nm;
            float ps = 0.f;
#pragma unroll
            for (int j = 0; j < 4; ++j) { float p = __expf(sv[i][j] - nm); sv[i][j] = p; ps += p; }
#pragma unroll
            for (int off = 1; off < 16; off <<= 1) ps += __shfl_xor(ps, off);
            l_run[i] = l_run[i] * fac + ps;
#pragma unroll
            for (int j = 0; j < 4; ++j) o_acc[i][j] *= fac;
            *(float4*)&Ps[ty * 4 + i][tx * 4] = make_float4(sv[i][0], sv[i][1], sv[i][2], sv[i][3]);
        }
        __syncthreads();

#pragma unroll 4
        for (int kk = 0; kk < MT; kk += 4) {
            float4 pm[4];
#pragma unroll
            for (int i = 0; i < 4; ++i) pm[i] = *(const float4*)&Ps[ty * 4 + i][kk];
#pragma unroll
            for (int t = 0; t < 4; ++t) {
                const float4 vv = *(const float4*)&Vs[kk + t][tx * 4];
                const float va[4] = {vv.x, vv.y, vv.z, vv.w};
                const float pa[4] = {pm[0].x, pm[1].x, pm[2].x, pm[3].x};
                const float pb[4] = {pm[0].y, pm[1].y, pm[2].y, pm[3].y};
                const float pc[4] = {pm[0].z, pm[1].z, pm[2].z, pm[3].z};
                const float pd[4] = {pm[0].w, pm[1].w, pm[2].w, pm[3].w};
                const float* psel = (t == 0) ? pa : (t == 1) ? pb : (t == 2) ? pc : pd;
#pragma unroll
                for (int i = 0; i < 4; ++i)
#pragma unroll
                    for (int j = 0; j < 4; ++j) o_acc[i][j] += psel[i] * va[j];
            }
        }
    }

#pragma unroll
    for (int i = 0; i < 4; ++i) {
        const float inv = 1.0f / l_run[i];
        half4v pk;
#pragma unroll
        for (int j = 0; j < 4; ++j) pk[j] = (_Float16)(o_acc[i][j] * inv);
        *(half4v*)&o[(size_t)(b * CN + r0 + i) * CD + h * CHD + tx * 4] = pk;
    }
}

// ---------------- driver ----------------------------------------------------
extern "C" void kernel_launch(void* const* d_in, const int* in_sizes, int n_in,
                              void* d_out, int out_size, void* d_ws, size_t ws_size,
                              hipStream_t stream) {
    const float* x      = (const float*)d_in[0];
    const int*   mask   = (const int*)d_in[1];
    const float* inter  = (const float*)d_in[2];
    const float* w_qkv  = (const float*)d_in[3];
    const float* b_qkv  = (const float*)d_in[4];
    const float* w_out  = (const float*)d_in[5];
    const float* b_out  = (const float*)d_in[6];
    const float* w1     = (const float*)d_in[7];
    const float* b1     = (const float*)d_in[8];
    const float* w2     = (const float*)d_in[9];
    const float* b2     = (const float*)d_in[10];
    const float* g_pre  = (const float*)d_in[11];
    const float* be_pre = (const float*)d_in[12];
    const float* g_post = (const float*)d_in[13];
    const float* be_post= (const float*)d_in[14];
    const float* g_ffn  = (const float*)d_in[15];
    const float* be_ffn = (const float*)d_in[16];
    const float* g_mid  = (const float*)d_in[17];
    const float* be_mid = (const float*)d_in[18];
    float* out = (float*)d_out;

    char* ws = (char*)d_ws;
    const size_t MB = 1ull << 20;
    _Float16* wt_qkv = (_Float16*)(ws + 0 * MB);      // 1536x512 f16 (1.5 MiB)
    _Float16* wt_out = (_Float16*)(ws + 2 * MB);      // 512x512   (0.5 MiB)
    _Float16* wt_w1  = (_Float16*)(ws + 3 * MB);      // 2048x512  (2 MiB)
    _Float16* wt_w2  = (_Float16*)(ws + 5 * MB);      // 512x2048  (2 MiB)
    float*    attended = (float*)(ws + 8 * MB);       // 32 MiB fp32
    void*     bigbuf   = (void*)(ws + 40 * MB);       // o2 fp32 (32MiB) then f1 f16 (64MiB)
    _Float16* qkvb   = (_Float16*)(ws + 104 * MB);    // 48 MiB
    _Float16* hb     = (_Float16*)(ws + 152 * MB);    // 16 MiB (h, later f)
    _Float16* ob     = (_Float16*)(ws + 168 * MB);    // 16 MiB

    const int M = CB * CN;  // 16384

    // weight prep
    transpose_f16<<<dim3(1536 / 32, 512 / 32), 256, 0, stream>>>(w_qkv, wt_qkv, 512, 1536);
    transpose_f16<<<dim3(512 / 32, 512 / 32), 256, 0, stream>>>(w_out, wt_out, 512, 512);
    transpose_f16<<<dim3(2048 / 32, 512 / 32), 256, 0, stream>>>(w1, wt_w1, 512, 2048);
    transpose_f16<<<dim3(512 / 32, 2048 / 32), 256, 0, stream>>>(w2, wt_w2, 2048, 512);

    // 1. h = LN(x) -> f16
    ln2_kernel<512, false, true, false><<<M / 4, 256, 0, stream>>>(x, g_pre, be_pre, nullptr, hb);
    // 2. qkv = h @ w_qkv + b_qkv -> f16
    gemm_f16<false, false, true><<<(M / 128) * (1536 / 128), 256, 0, stream>>>(
        hb, wt_qkv, b_qkv, nullptr, qkvb, M, 1536, 512);
    // 3. attention -> o f16
    attn_kernel<<<CB * (CN / 64) * CH, 256, 0, stream>>>(qkvb, inter, mask, ob);
    // 4. o2 = o @ w_out + b_out -> fp32
    gemm_f16<false, false, false><<<(M / 128) * (512 / 128), 256, 0, stream>>>(
        ob, wt_out, b_out, nullptr, bigbuf, M, 512, 512);
    // 5. attended = LN(o2) + x -> fp32
    ln2_kernel<512, false, false, true><<<M / 4, 256, 0, stream>>>(bigbuf, g_post, be_post, x, attended);
    // 6. f = LN(attended) -> f16 (reuse hb)
    ln2_kernel<512, false, true, false><<<M / 4, 256, 0, stream>>>(attended, g_ffn, be_ffn, nullptr, hb);
    // 7. f1 = gelu(f @ w1 + b1) -> f16 (bigbuf; o2 dead)
    gemm_f16<true, false, true><<<(M / 128) * (2048 / 128), 256, 0, stream>>>(
        hb, wt_w1, b1, nullptr, bigbuf, M, 2048, 512);
    // 8. f1 = LN(f1) in-place (f16 -> f16)
    ln2_kernel<2048, true, true, false><<<M / 4, 256, 0, stream>>>(bigbuf, g_mid, be_mid, nullptr, bigbuf);
    // 9. out = f1 @ w2 + b2 + attended -> fp32
    gemm_f16<false, true, false><<<(M / 128) * (512 / 128), 256, 0, stream>>>(
        (_Float16*)bigbuf, wt_w2, b2, attended, out, M, 512, 2048);
}

// Round 4
// 484.791 us; speedup vs baseline: 11.8640x; 1.4161x over previous
//
#include <hip/hip_runtime.h>
#include <hip/hip_bf16.h>
#include <math.h>

// Problem constants (B,N,D,H,E) = (32,512,512,8,4), HD=64
constexpr int CB = 32, CN = 512, CD = 512, CH = 8, CHD = 64;
constexpr float LN_EPS = 1e-3f;

typedef _Float16 half8 __attribute__((ext_vector_type(8)));
typedef _Float16 half4v __attribute__((ext_vector_type(4)));
typedef float f32x4 __attribute__((ext_vector_type(4)));

__device__ __forceinline__ void async16(const void* g, void* l) {
    __builtin_amdgcn_global_load_lds((const __attribute__((address_space(1))) void*)g,
                                     (__attribute__((address_space(3))) void*)l, 16, 0, 0);
}

// ---------------- weight transpose + fp32->f16: in[K][N] -> out[N][K] ------
__global__ __launch_bounds__(256) void transpose_f16(const float* __restrict__ in,
                                                     _Float16* __restrict__ out,
                                                     int K, int N) {
    __shared__ float t[32][33];
    const int tx = threadIdx.x % 32, ty = threadIdx.x / 32;
    const int n0 = blockIdx.x * 32, k0 = blockIdx.y * 32;
#pragma unroll
    for (int i = 0; i < 4; ++i)
        t[ty + i * 8][tx] = in[(size_t)(k0 + ty + i * 8) * N + n0 + tx];
    __syncthreads();
#pragma unroll
    for (int i = 0; i < 4; ++i)
        out[(size_t)(n0 + ty + i * 8) * K + k0 + tx] = (_Float16)t[tx][ty + i * 8];
}

// ---------------- bias pre-pass: bias[bl,h,n,m] = inter[b,n,m,h] + mask -----
__global__ __launch_bounds__(256) void bias_prepass(const float* __restrict__ inter,
        const int* __restrict__ mask, _Float16* __restrict__ bias, int b0) {
    const size_t idx = (size_t)blockIdx.x * 256 + threadIdx.x;  // bl*N*N + n*N + m
    const size_t gidx = (size_t)b0 * CN * CN + idx;
    float4 v0 = *(const float4*)(inter + gidx * 8);
    float4 v1 = *(const float4*)(inter + gidx * 8 + 4);
    const float add = mask[gidx] ? 0.f : -30000.f;
    const float vals[8] = {v0.x, v0.y, v0.z, v0.w, v1.x, v1.y, v1.z, v1.w};
    const size_t plane = (size_t)CN * CN;
    const size_t bl = idx / plane;
    const size_t nm = idx % plane;
    _Float16* outp = bias + bl * CH * plane + nm;
#pragma unroll
    for (int h = 0; h < 8; ++h) outp[h * plane] = (_Float16)(vals[h] + add);
}

// ---------------- LayerNorm, wave per row -----------------------------------
template<int WIDTH, bool IN_F16, bool OUT_F16, bool ADDRES>
__global__ __launch_bounds__(256) void ln2_kernel(const void* __restrict__ in_,
        const float* __restrict__ g, const float* __restrict__ be,
        const float* __restrict__ res, void* __restrict__ out_) {
    constexpr int NPL = WIDTH / 64;
    const int row = blockIdx.x * 4 + (threadIdx.x >> 6);
    const int lane = threadIdx.x & 63;
    const int c0 = lane * NPL;
    float v[NPL];
    if (IN_F16) {
        const _Float16* p = (const _Float16*)in_ + (size_t)row * WIDTH + c0;
#pragma unroll
        for (int i = 0; i < NPL / 8; ++i) {
            half8 u = *(const half8*)(p + i * 8);
#pragma unroll
            for (int j = 0; j < 8; ++j) v[i * 8 + j] = (float)u[j];
        }
    } else {
        const float* p = (const float*)in_ + (size_t)row * WIDTH + c0;
#pragma unroll
        for (int i = 0; i < NPL / 4; ++i) {
            float4 u = *(const float4*)(p + i * 4);
            v[i * 4 + 0] = u.x; v[i * 4 + 1] = u.y; v[i * 4 + 2] = u.z; v[i * 4 + 3] = u.w;
        }
    }
    float s1 = 0.f, s2 = 0.f;
#pragma unroll
    for (int i = 0; i < NPL; ++i) { s1 += v[i]; s2 += v[i] * v[i]; }
#pragma unroll
    for (int off = 1; off < 64; off <<= 1) { s1 += __shfl_xor(s1, off); s2 += __shfl_xor(s2, off); }
    const float mean = s1 * (1.0f / WIDTH);
    const float var = s2 * (1.0f / WIDTH) - mean * mean;
    const float rstd = rsqrtf(var + LN_EPS);

    float ov[NPL];
#pragma unroll
    for (int i = 0; i < NPL / 4; ++i) {
        float4 gv = *(const float4*)(g + c0 + i * 4);
        float4 bv = *(const float4*)(be + c0 + i * 4);
        ov[i * 4 + 0] = (v[i * 4 + 0] - mean) * rstd * gv.x + bv.x;
        ov[i * 4 + 1] = (v[i * 4 + 1] - mean) * rstd * gv.y + bv.y;
        ov[i * 4 + 2] = (v[i * 4 + 2] - mean) * rstd * gv.z + bv.z;
        ov[i * 4 + 3] = (v[i * 4 + 3] - mean) * rstd * gv.w + bv.w;
    }
    if (ADDRES) {
        const float* rp = res + (size_t)row * WIDTH + c0;
#pragma unroll
        for (int i = 0; i < NPL / 4; ++i) {
            float4 rv = *(const float4*)(rp + i * 4);
            ov[i * 4 + 0] += rv.x; ov[i * 4 + 1] += rv.y; ov[i * 4 + 2] += rv.z; ov[i * 4 + 3] += rv.w;
        }
    }
    if (OUT_F16) {
        _Float16* po = (_Float16*)out_ + (size_t)row * WIDTH + c0;
#pragma unroll
        for (int i = 0; i < NPL / 8; ++i) {
            half8 hv;
#pragma unroll
            for (int j = 0; j < 8; ++j) hv[j] = (_Float16)ov[i * 8 + j];
            *(half8*)(po + i * 8) = hv;
        }
    } else {
        float* po = (float*)out_ + (size_t)row * WIDTH + c0;
#pragma unroll
        for (int i = 0; i < NPL / 4; ++i) {
            float4 w = make_float4(ov[i * 4 + 0], ov[i * 4 + 1], ov[i * 4 + 2], ov[i * 4 + 3]);
            *(float4*)(po + i * 4) = w;
        }
    }
}

// ---------------- f16 MFMA GEMM: C = A[M,K] @ Wt[N,K]^T + bias --------------
template<bool GELU, bool RES, bool OUT_F16>
__global__ __launch_bounds__(256) void gemm_f16(const _Float16* __restrict__ A,
        const _Float16* __restrict__ Wt, const float* __restrict__ bias,
        const float* __restrict__ res, void* __restrict__ Cout,
        int M, int N, int K) {
    __shared__ __align__(16) char As[16384];
    __shared__ __align__(16) char Bs[16384];
    const int tid = threadIdx.x;
    const int nbx = N >> 7;
    const int nwg = (M >> 7) * nbx;
    int gb = blockIdx.x;
    gb = (gb & 7) * (nwg >> 3) + (gb >> 3);   // XCD swizzle (nwg % 8 == 0)
    const int by = gb / nbx, bx = gb % nbx;

    const int lane = tid & 63;
    const int wv = tid >> 6;
    const int rsub = lane >> 3;
    const int slot = lane & 7;
    const int chunk = slot ^ rsub;
    const _Float16* Abase = A + (size_t)(by * 128) * K + chunk * 8;
    const _Float16* Bbase = Wt + (size_t)(bx * 128) * K + chunk * 8;

    const int wm = wv >> 1, wn = wv & 1;
    const int lrow = lane & 15;
    const int lk = lane >> 4;
    const int xorv = lane & 7;
    const int aRowB = (wm * 64 + lrow) * 128;
    const int bRowB = (wn * 64 + lrow) * 128;

    f32x4 acc[4][4] = {};

    for (int k0 = 0; k0 < K; k0 += 64) {
#pragma unroll
        for (int t = 0; t < 4; ++t) {
            const int rowb = t * 32 + wv * 8;
            async16(Abase + (size_t)(rowb + rsub) * K + k0, As + rowb * 128);
            async16(Bbase + (size_t)(rowb + rsub) * K + k0, Bs + rowb * 128);
        }
        __syncthreads();
#pragma unroll
        for (int kk = 0; kk < 2; ++kk) {
            const int sa = ((kk * 4 + lk) ^ xorv) << 4;
            half8 af[4], bf[4];
#pragma unroll
            for (int mi = 0; mi < 4; ++mi) af[mi] = *(const half8*)(As + aRowB + mi * 2048 + sa);
#pragma unroll
            for (int ni = 0; ni < 4; ++ni) bf[ni] = *(const half8*)(Bs + bRowB + ni * 2048 + sa);
#pragma unroll
            for (int mi = 0; mi < 4; ++mi)
#pragma unroll
                for (int ni = 0; ni < 4; ++ni)
                    acc[mi][ni] = __builtin_amdgcn_mfma_f32_16x16x32_f16(af[mi], bf[ni], acc[mi][ni], 0, 0, 0);
        }
        __syncthreads();
    }

    const int lr4 = (lane >> 4) * 4;
    const int lc = lane & 15;
#pragma unroll
    for (int ni = 0; ni < 4; ++ni) {
        const int colg = bx * 128 + wn * 64 + ni * 16 + lc;
        const float bv = bias[colg];
#pragma unroll
        for (int mi = 0; mi < 4; ++mi) {
            const int rowg = by * 128 + wm * 64 + mi * 16 + lr4;
#pragma unroll
            for (int r = 0; r < 4; ++r) {
                float v = acc[mi][ni][r] + bv;
                if (GELU) v = 0.5f * v * (1.0f + erff(v * 0.70710678118654752440f));
                if (RES) v += res[(size_t)(rowg + r) * N + colg];
                if (OUT_F16) ((_Float16*)Cout)[(size_t)(rowg + r) * N + colg] = (_Float16)v;
                else ((float*)Cout)[(size_t)(rowg + r) * N + colg] = v;
            }
        }
    }
}

// ---------------- MFMA flash attention --------------------------------------
// Block = (b, h, q-tile 64). 4 waves x 16 q-rows. bias: [16b-half, H, N, N] f16.
__global__ __launch_bounds__(256) void attn_mfma(
        const _Float16* __restrict__ qkv, const _Float16* __restrict__ bias,
        _Float16* __restrict__ o, int b0) {
    const int bid = blockIdx.x;
    const int h  = bid & 7;
    const int qt = (bid >> 3) & 7;
    const int bl = bid >> 6;
    const int b  = b0 + bl;
    const int tid = threadIdx.x;
    const int lane = tid & 63;
    const int w = tid >> 6;
    const int l15 = lane & 15, l4 = lane >> 4;

    __shared__ __align__(16) char Qs[8192];
    __shared__ __align__(16) char Ks[8192];
    __shared__ __align__(16) char Vt[8192];
    __shared__ __align__(16) char Ps[8192];

    constexpr size_t QKVROW = 1536;
    // stage Q (64 rows x 128B), chunk-swizzled
    {
        const _Float16* Qg = qkv + (size_t)(b * CN + qt * 64) * QKVROW + h * 64;
#pragma unroll
        for (int p = 0; p < 2; ++p) {
            const int f = tid + 256 * p;
            const int r = f >> 3, c = f & 7;
            half8 v = *(const half8*)(Qg + (size_t)r * QKVROW + c * 8);
            *(half8*)(Qs + r * 128 + ((c ^ (r & 7)) << 4)) = v;
        }
    }

    f32x4 acc_o[4] = {};
    float m_run[4] = {-3e38f, -3e38f, -3e38f, -3e38f};
    float l_run[4] = {0.f, 0.f, 0.f, 0.f};

    const _Float16* biasBase = bias + ((size_t)(bl * CH + h) * CN + qt * 64) * CN;

    for (int mt = 0; mt < 8; ++mt) {
        __syncthreads();
        const _Float16* Kg = qkv + (size_t)(b * CN + mt * 64) * QKVROW + 512 + h * 64;
        const _Float16* Vg = Kg + 512;
#pragma unroll
        for (int p = 0; p < 2; ++p) {
            const int f = tid + 256 * p;
            const int r = f >> 3, c = f & 7;
            half8 kv = *(const half8*)(Kg + (size_t)r * QKVROW + c * 8);
            *(half8*)(Ks + r * 128 + ((c ^ (r & 7)) << 4)) = kv;
        }
#pragma unroll
        for (int p = 0; p < 2; ++p) {
            const int f = tid + 256 * p;
            const int m = f >> 3, dc = f & 7;
            half8 vv = *(const half8*)(Vg + (size_t)m * QKVROW + dc * 8);
            const int mc = m >> 3, mo = m & 7;
#pragma unroll
            for (int j = 0; j < 8; ++j) {
                const int d = dc * 8 + j;
                *(_Float16*)(Vt + d * 128 + ((mc ^ (d & 7)) << 4) + mo * 2) = vv[j];
            }
        }
        __syncthreads();

        // QK^T: S[16q x 64m] per wave
        f32x4 acc_s[4] = {};
#pragma unroll
        for (int step = 0; step < 2; ++step) {
            const int qrow = w * 16 + l15;
            const int ch = step * 4 + l4;
            half8 aq = *(const half8*)(Qs + qrow * 128 + ((ch ^ (qrow & 7)) << 4));
#pragma unroll
            for (int mi = 0; mi < 4; ++mi) {
                const int mrow = mi * 16 + l15;
                half8 bk = *(const half8*)(Ks + mrow * 128 + ((ch ^ (mrow & 7)) << 4));
                acc_s[mi] = __builtin_amdgcn_mfma_f32_16x16x32_f16(aq, bk, acc_s[mi], 0, 0, 0);
            }
        }
        // bias + online softmax (row q = w*16 + l4*4 + r; col m = mi*16 + l15)
#pragma unroll
        for (int r = 0; r < 4; ++r) {
            const _Float16* brow = biasBase + (size_t)(w * 16 + l4 * 4 + r) * CN + mt * 64 + l15;
            float pv[4];
            float rmax = -3e38f;
#pragma unroll
            for (int mi = 0; mi < 4; ++mi) {
                float s = acc_s[mi][r] * 0.125f + (float)brow[mi * 16];
                pv[mi] = s;
                rmax = fmaxf(rmax, s);
            }
#pragma unroll
            for (int off = 1; off < 16; off <<= 1) rmax = fmaxf(rmax, __shfl_xor(rmax, off));
            const float nm = fmaxf(m_run[r], rmax);
            const float fac = __expf(m_run[r] - nm);
            m_run[r] = nm;
            float ps = 0.f;
#pragma unroll
            for (int mi = 0; mi < 4; ++mi) { float e = __expf(pv[mi] - nm); pv[mi] = e; ps += e; }
#pragma unroll
            for (int off = 1; off < 16; off <<= 1) ps += __shfl_xor(ps, off);
            l_run[r] = l_run[r] * fac + ps;
#pragma unroll
            for (int di = 0; di < 4; ++di) acc_o[di][r] *= fac;
            const int qrow = w * 16 + l4 * 4 + r;
#pragma unroll
            for (int mi = 0; mi < 4; ++mi) {
                const int m = mi * 16 + l15;
                *(_Float16*)(Ps + qrow * 128 + (((m >> 3) ^ (qrow & 7)) << 4) + (m & 7) * 2) = (_Float16)pv[mi];
            }
        }
        // PV: O[16q x 64d] += P @ V  (Vt rows = d, k = m)
#pragma unroll
        for (int step = 0; step < 2; ++step) {
            const int qrow = w * 16 + l15;
            const int ch = step * 4 + l4;
            half8 ap = *(const half8*)(Ps + qrow * 128 + ((ch ^ (qrow & 7)) << 4));
#pragma unroll
            for (int di = 0; di < 4; ++di) {
                const int drow = di * 16 + l15;
                half8 bv = *(const half8*)(Vt + drow * 128 + ((ch ^ (drow & 7)) << 4));
                acc_o[di] = __builtin_amdgcn_mfma_f32_16x16x32_f16(ap, bv, acc_o[di], 0, 0, 0);
            }
        }
    }
    // epilogue
    _Float16* orow = o + (size_t)(b * CN + qt * 64 + w * 16 + l4 * 4) * CD + h * 64 + l15;
#pragma unroll
    for (int r = 0; r < 4; ++r) {
        const float inv = 1.0f / l_run[r];
#pragma unroll
        for (int di = 0; di < 4; ++di)
            orow[(size_t)r * CD + di * 16] = (_Float16)(acc_o[di][r] * inv);
    }
}

// ---------------- driver ----------------------------------------------------
extern "C" void kernel_launch(void* const* d_in, const int* in_sizes, int n_in,
                              void* d_out, int out_size, void* d_ws, size_t ws_size,
                              hipStream_t stream) {
    const float* x      = (const float*)d_in[0];
    const int*   mask   = (const int*)d_in[1];
    const float* inter  = (const float*)d_in[2];
    const float* w_qkv  = (const float*)d_in[3];
    const float* b_qkv  = (const float*)d_in[4];
    const float* w_out  = (const float*)d_in[5];
    const float* b_out  = (const float*)d_in[6];
    const float* w1     = (const float*)d_in[7];
    const float* b1     = (const float*)d_in[8];
    const float* w2     = (const float*)d_in[9];
    const float* b2     = (const float*)d_in[10];
    const float* g_pre  = (const float*)d_in[11];
    const float* be_pre = (const float*)d_in[12];
    const float* g_post = (const float*)d_in[13];
    const float* be_post= (const float*)d_in[14];
    const float* g_ffn  = (const float*)d_in[15];
    const float* be_ffn = (const float*)d_in[16];
    const float* g_mid  = (const float*)d_in[17];
    const float* be_mid = (const float*)d_in[18];
    float* out = (float*)d_out;

    char* ws = (char*)d_ws;
    const size_t MB = 1ull << 20;
    _Float16* wt_qkv = (_Float16*)(ws + 0 * MB);
    _Float16* wt_out = (_Float16*)(ws + 2 * MB);
    _Float16* wt_w1  = (_Float16*)(ws + 3 * MB);
    _Float16* wt_w2  = (_Float16*)(ws + 5 * MB);
    float*    attended = (float*)(ws + 8 * MB);       // [8,40)
    _Float16* biasb  = (_Float16*)(ws + 40 * MB);     // [40,104) 64 MiB (half-batch), later bigbuf
    void*     bigbuf = (void*)(ws + 40 * MB);         // o2 fp32 / f1 f16 (after attention)
    _Float16* qkvb   = (_Float16*)(ws + 104 * MB);    // [104,152)
    _Float16* hb     = (_Float16*)(ws + 152 * MB);    // [152,168)
    _Float16* ob     = (_Float16*)(ws + 168 * MB);    // [168,184)

    const int M = CB * CN;  // 16384

    // weight prep
    transpose_f16<<<dim3(1536 / 32, 512 / 32), 256, 0, stream>>>(w_qkv, wt_qkv, 512, 1536);
    transpose_f16<<<dim3(512 / 32, 512 / 32), 256, 0, stream>>>(w_out, wt_out, 512, 512);
    transpose_f16<<<dim3(2048 / 32, 512 / 32), 256, 0, stream>>>(w1, wt_w1, 512, 2048);
    transpose_f16<<<dim3(512 / 32, 2048 / 32), 256, 0, stream>>>(w2, wt_w2, 2048, 512);

    // 1. h = LN(x) -> f16
    ln2_kernel<512, false, true, false><<<M / 4, 256, 0, stream>>>(x, g_pre, be_pre, nullptr, hb);
    // 2. qkv = h @ w_qkv + b_qkv -> f16
    gemm_f16<false, false, true><<<(M / 128) * (1536 / 128), 256, 0, stream>>>(
        hb, wt_qkv, b_qkv, nullptr, qkvb, M, 1536, 512);
    // 3. attention in two b-halves: bias pre-pass + MFMA flash attention
    for (int half = 0; half < 2; ++half) {
        const int b0 = half * 16;
        bias_prepass<<<16 * CN * CN / 256, 256, 0, stream>>>(inter, mask, biasb, b0);
        attn_mfma<<<16 * 8 * 8, 256, 0, stream>>>(qkvb, biasb, ob, b0);
    }
    // 4. o2 = o @ w_out + b_out -> fp32 (bigbuf; bias dead)
    gemm_f16<false, false, false><<<(M / 128) * (512 / 128), 256, 0, stream>>>(
        ob, wt_out, b_out, nullptr, bigbuf, M, 512, 512);
    // 5. attended = LN(o2) + x -> fp32
    ln2_kernel<512, false, false, true><<<M / 4, 256, 0, stream>>>(bigbuf, g_post, be_post, x, attended);
    // 6. f = LN(attended) -> f16
    ln2_kernel<512, false, true, false><<<M / 4, 256, 0, stream>>>(attended, g_ffn, be_ffn, nullptr, hb);
    // 7. f1 = gelu(f @ w1 + b1) -> f16
    gemm_f16<true, false, true><<<(M / 128) * (2048 / 128), 256, 0, stream>>>(
        hb, wt_w1, b1, nullptr, bigbuf, M, 2048, 512);
    // 8. f1 = LN(f1) in-place
    ln2_kernel<2048, true, true, false><<<M / 4, 256, 0, stream>>>(bigbuf, g_mid, be_mid, nullptr, bigbuf);
    // 9. out = f1 @ w2 + b2 + attended -> fp32
    gemm_f16<false, true, false><<<(M / 128) * (512 / 128), 256, 0, stream>>>(
        (_Float16*)bigbuf, wt_w2, b2, attended, out, M, 512, 2048);
}

// Round 5
// 460.939 us; speedup vs baseline: 12.4779x; 1.0517x over previous
//
#include <hip/hip_runtime.h>
#include <hip/hip_bf16.h>
#include <math.h>

// Problem constants (B,N,D,H,E) = (32,512,512,8,4), HD=64
constexpr int CB = 32, CN = 512, CD = 512, CH = 8, CHD = 64;
constexpr float LN_EPS = 1e-3f;

typedef _Float16 half8 __attribute__((ext_vector_type(8)));
typedef float f32x4 __attribute__((ext_vector_type(4)));

__device__ __forceinline__ void async16(const void* g, void* l) {
    __builtin_amdgcn_global_load_lds((const __attribute__((address_space(1))) void*)g,
                                     (__attribute__((address_space(3))) void*)l, 16, 0, 0);
}

// ---------------- weight transpose + fp32->f16: in[K][N] -> out[N][K] ------
__global__ __launch_bounds__(256) void transpose_f16(const float* __restrict__ in,
                                                     _Float16* __restrict__ out,
                                                     int K, int N) {
    __shared__ float t[32][33];
    const int tx = threadIdx.x % 32, ty = threadIdx.x / 32;
    const int n0 = blockIdx.x * 32, k0 = blockIdx.y * 32;
#pragma unroll
    for (int i = 0; i < 4; ++i)
        t[ty + i * 8][tx] = in[(size_t)(k0 + ty + i * 8) * N + n0 + tx];
    __syncthreads();
#pragma unroll
    for (int i = 0; i < 4; ++i)
        out[(size_t)(n0 + ty + i * 8) * K + k0 + tx] = (_Float16)t[tx][ty + i * 8];
}

// ---------------- LayerNorm, wave per row -----------------------------------
template<int WIDTH, bool IN_F16, bool OUT_F16, bool ADDRES>
__global__ __launch_bounds__(256) void ln2_kernel(const void* __restrict__ in_,
        const float* __restrict__ g, const float* __restrict__ be,
        const float* __restrict__ res, void* __restrict__ out_) {
    constexpr int NPL = WIDTH / 64;
    const int row = blockIdx.x * 4 + (threadIdx.x >> 6);
    const int lane = threadIdx.x & 63;
    const int c0 = lane * NPL;
    float v[NPL];
    if (IN_F16) {
        const _Float16* p = (const _Float16*)in_ + (size_t)row * WIDTH + c0;
#pragma unroll
        for (int i = 0; i < NPL / 8; ++i) {
            half8 u = *(const half8*)(p + i * 8);
#pragma unroll
            for (int j = 0; j < 8; ++j) v[i * 8 + j] = (float)u[j];
        }
    } else {
        const float* p = (const float*)in_ + (size_t)row * WIDTH + c0;
#pragma unroll
        for (int i = 0; i < NPL / 4; ++i) {
            float4 u = *(const float4*)(p + i * 4);
            v[i * 4 + 0] = u.x; v[i * 4 + 1] = u.y; v[i * 4 + 2] = u.z; v[i * 4 + 3] = u.w;
        }
    }
    float s1 = 0.f, s2 = 0.f;
#pragma unroll
    for (int i = 0; i < NPL; ++i) { s1 += v[i]; s2 += v[i] * v[i]; }
#pragma unroll
    for (int off = 1; off < 64; off <<= 1) { s1 += __shfl_xor(s1, off); s2 += __shfl_xor(s2, off); }
    const float mean = s1 * (1.0f / WIDTH);
    const float var = s2 * (1.0f / WIDTH) - mean * mean;
    const float rstd = rsqrtf(var + LN_EPS);

    float ov[NPL];
#pragma unroll
    for (int i = 0; i < NPL / 4; ++i) {
        float4 gv = *(const float4*)(g + c0 + i * 4);
        float4 bv = *(const float4*)(be + c0 + i * 4);
        ov[i * 4 + 0] = (v[i * 4 + 0] - mean) * rstd * gv.x + bv.x;
        ov[i * 4 + 1] = (v[i * 4 + 1] - mean) * rstd * gv.y + bv.y;
        ov[i * 4 + 2] = (v[i * 4 + 2] - mean) * rstd * gv.z + bv.z;
        ov[i * 4 + 3] = (v[i * 4 + 3] - mean) * rstd * gv.w + bv.w;
    }
    if (ADDRES) {
        const float* rp = res + (size_t)row * WIDTH + c0;
#pragma unroll
        for (int i = 0; i < NPL / 4; ++i) {
            float4 rv = *(const float4*)(rp + i * 4);
            ov[i * 4 + 0] += rv.x; ov[i * 4 + 1] += rv.y; ov[i * 4 + 2] += rv.z; ov[i * 4 + 3] += rv.w;
        }
    }
    if (OUT_F16) {
        _Float16* po = (_Float16*)out_ + (size_t)row * WIDTH + c0;
#pragma unroll
        for (int i = 0; i < NPL / 8; ++i) {
            half8 hv;
#pragma unroll
            for (int j = 0; j < 8; ++j) hv[j] = (_Float16)ov[i * 8 + j];
            *(half8*)(po + i * 8) = hv;
        }
    } else {
        float* po = (float*)out_ + (size_t)row * WIDTH + c0;
#pragma unroll
        for (int i = 0; i < NPL / 4; ++i) {
            float4 w = make_float4(ov[i * 4 + 0], ov[i * 4 + 1], ov[i * 4 + 2], ov[i * 4 + 3]);
            *(float4*)(po + i * 4) = w;
        }
    }
}

// ---------------- fused: attended = LN(o2)+x ; f = LN(attended) -------------
// o2: f16 [row,512]; x: fp32; attended: fp32 out; f: f16 out. Wave per row.
__global__ __launch_bounds__(256) void ln_post_ffn(const _Float16* __restrict__ o2,
        const float* __restrict__ x,
        const float* __restrict__ g_post, const float* __restrict__ be_post,
        const float* __restrict__ g_ffn, const float* __restrict__ be_ffn,
        float* __restrict__ attended, _Float16* __restrict__ f) {
    constexpr int NPL = 8;
    const int row = blockIdx.x * 4 + (threadIdx.x >> 6);
    const int lane = threadIdx.x & 63;
    const int c0 = lane * NPL;
    float v[NPL], xv[NPL];
    {
        half8 u = *(const half8*)(o2 + (size_t)row * CD + c0);
#pragma unroll
        for (int j = 0; j < 8; ++j) v[j] = (float)u[j];
        float4 a = *(const float4*)(x + (size_t)row * CD + c0);
        float4 b = *(const float4*)(x + (size_t)row * CD + c0 + 4);
        xv[0] = a.x; xv[1] = a.y; xv[2] = a.z; xv[3] = a.w;
        xv[4] = b.x; xv[5] = b.y; xv[6] = b.z; xv[7] = b.w;
    }
    float s1 = 0.f, s2 = 0.f;
#pragma unroll
    for (int i = 0; i < NPL; ++i) { s1 += v[i]; s2 += v[i] * v[i]; }
#pragma unroll
    for (int off = 1; off < 64; off <<= 1) { s1 += __shfl_xor(s1, off); s2 += __shfl_xor(s2, off); }
    float mean = s1 * (1.0f / CD);
    float rstd = rsqrtf(s2 * (1.0f / CD) - mean * mean + LN_EPS);
    float av[NPL];
#pragma unroll
    for (int i = 0; i < NPL; ++i)
        av[i] = (v[i] - mean) * rstd * g_post[c0 + i] + be_post[c0 + i] + xv[i];
    {
        float4 w0 = make_float4(av[0], av[1], av[2], av[3]);
        float4 w1 = make_float4(av[4], av[5], av[6], av[7]);
        *(float4*)(attended + (size_t)row * CD + c0) = w0;
        *(float4*)(attended + (size_t)row * CD + c0 + 4) = w1;
    }
    // second LN over attended
    s1 = 0.f; s2 = 0.f;
#pragma unroll
    for (int i = 0; i < NPL; ++i) { s1 += av[i]; s2 += av[i] * av[i]; }
#pragma unroll
    for (int off = 1; off < 64; off <<= 1) { s1 += __shfl_xor(s1, off); s2 += __shfl_xor(s2, off); }
    mean = s1 * (1.0f / CD);
    rstd = rsqrtf(s2 * (1.0f / CD) - mean * mean + LN_EPS);
    half8 hv;
#pragma unroll
    for (int i = 0; i < NPL; ++i)
        hv[i] = (_Float16)((av[i] - mean) * rstd * g_ffn[c0 + i] + be_ffn[c0 + i]);
    *(half8*)(f + (size_t)row * CD + c0) = hv;
}

// ---------------- f16 MFMA GEMM: C = A[M,K] @ Wt[N,K]^T + bias --------------
template<bool GELU, bool RES, bool OUT_F16>
__global__ __launch_bounds__(256) void gemm_f16(const _Float16* __restrict__ A,
        const _Float16* __restrict__ Wt, const float* __restrict__ bias,
        const float* __restrict__ res, void* __restrict__ Cout,
        int M, int N, int K) {
    __shared__ __align__(16) char As[16384];
    __shared__ __align__(16) char Bs[16384];
    const int tid = threadIdx.x;
    const int nbx = N >> 7;
    const int nwg = (M >> 7) * nbx;
    int gb = blockIdx.x;
    gb = (gb & 7) * (nwg >> 3) + (gb >> 3);   // XCD swizzle (nwg % 8 == 0)
    const int by = gb / nbx, bx = gb % nbx;

    const int lane = tid & 63;
    const int wv = tid >> 6;
    const int rsub = lane >> 3;
    const int slot = lane & 7;
    const int chunk = slot ^ rsub;
    const _Float16* Abase = A + (size_t)(by * 128) * K + chunk * 8;
    const _Float16* Bbase = Wt + (size_t)(bx * 128) * K + chunk * 8;

    const int wm = wv >> 1, wn = wv & 1;
    const int lrow = lane & 15;
    const int lk = lane >> 4;
    const int xorv = lane & 7;
    const int aRowB = (wm * 64 + lrow) * 128;
    const int bRowB = (wn * 64 + lrow) * 128;

    f32x4 acc[4][4] = {};

    for (int k0 = 0; k0 < K; k0 += 64) {
#pragma unroll
        for (int t = 0; t < 4; ++t) {
            const int rowb = t * 32 + wv * 8;
            async16(Abase + (size_t)(rowb + rsub) * K + k0, As + rowb * 128);
            async16(Bbase + (size_t)(rowb + rsub) * K + k0, Bs + rowb * 128);
        }
        __syncthreads();
#pragma unroll
        for (int kk = 0; kk < 2; ++kk) {
            const int sa = ((kk * 4 + lk) ^ xorv) << 4;
            half8 af[4], bf[4];
#pragma unroll
            for (int mi = 0; mi < 4; ++mi) af[mi] = *(const half8*)(As + aRowB + mi * 2048 + sa);
#pragma unroll
            for (int ni = 0; ni < 4; ++ni) bf[ni] = *(const half8*)(Bs + bRowB + ni * 2048 + sa);
#pragma unroll
            for (int mi = 0; mi < 4; ++mi)
#pragma unroll
                for (int ni = 0; ni < 4; ++ni)
                    acc[mi][ni] = __builtin_amdgcn_mfma_f32_16x16x32_f16(af[mi], bf[ni], acc[mi][ni], 0, 0, 0);
        }
        __syncthreads();
    }

    const int lr4 = (lane >> 4) * 4;
    const int lc = lane & 15;
#pragma unroll
    for (int ni = 0; ni < 4; ++ni) {
        const int colg = bx * 128 + wn * 64 + ni * 16 + lc;
        const float bv = bias[colg];
#pragma unroll
        for (int mi = 0; mi < 4; ++mi) {
            const int rowg = by * 128 + wm * 64 + mi * 16 + lr4;
#pragma unroll
            for (int r = 0; r < 4; ++r) {
                float v = acc[mi][ni][r] + bv;
                if (GELU) v = 0.5f * v * (1.0f + erff(v * 0.70710678118654752440f));
                if (RES) v += res[(size_t)(rowg + r) * N + colg];
                if (OUT_F16) ((_Float16*)Cout)[(size_t)(rowg + r) * N + colg] = (_Float16)v;
                else ((float*)Cout)[(size_t)(rowg + r) * N + colg] = v;
            }
        }
    }
}

// ---------------- MFMA flash attention, direct inter/mask consumption -------
// Grid 2048. Decode puts b%8 = bid&7 (XCD pin: per-XCD working set = one batch's
// K/V + inter lines), h-minor so the 8 h-siblings sharing inter cachelines are
// adjacent dispatches on the same XCD.
__global__ __launch_bounds__(256) void attn_mfma(
        const _Float16* __restrict__ qkv, const float* __restrict__ inter,
        const int* __restrict__ mask, _Float16* __restrict__ o) {
    const int bid = blockIdx.x;
    const int xcd = bid & 7;
    const int s = bid >> 3;
    const int h = s & 7;
    const int qt = (s >> 3) & 7;
    const int b = (s >> 6) * 8 + xcd;
    const int tid = threadIdx.x;
    const int lane = tid & 63;
    const int w = tid >> 6;
    const int l15 = lane & 15, l4 = lane >> 4;

    __shared__ __align__(16) char Qs[8192];
    __shared__ __align__(16) char Ks[8192];
    __shared__ __align__(16) char Vt[8192];
    __shared__ __align__(16) char Ps[8192];

    constexpr size_t QKVROW = 1536;
    // stage Q (64 rows x 128B), chunk-swizzled
    {
        const _Float16* Qg = qkv + (size_t)(b * CN + qt * 64) * QKVROW + h * 64;
#pragma unroll
        for (int p = 0; p < 2; ++p) {
            const int f = tid + 256 * p;
            const int r = f >> 3, c = f & 7;
            half8 v = *(const half8*)(Qg + (size_t)r * QKVROW + c * 8);
            *(half8*)(Qs + r * 128 + ((c ^ (r & 7)) << 4)) = v;
        }
    }

    f32x4 acc_o[4] = {};
    float m_run[4] = {-3e38f, -3e38f, -3e38f, -3e38f};
    float l_run[4] = {0.f, 0.f, 0.f, 0.f};

    // per-r row bases for inter/mask (q row = qt*64 + w*16 + l4*4 + r)
    const int qg0 = qt * 64 + w * 16 + l4 * 4;
    const float* interB[4];
    const int* maskB[4];
#pragma unroll
    for (int r = 0; r < 4; ++r) {
        interB[r] = inter + ((size_t)(b * CN + qg0 + r) * CN) * CH + h;
        maskB[r]  = mask + (size_t)(b * CN + qg0 + r) * CN;
    }

    for (int mt = 0; mt < 8; ++mt) {
        __syncthreads();
        const _Float16* Kg = qkv + (size_t)(b * CN + mt * 64) * QKVROW + 512 + h * 64;
        const _Float16* Vg = Kg + 512;
#pragma unroll
        for (int p = 0; p < 2; ++p) {
            const int f = tid + 256 * p;
            const int r = f >> 3, c = f & 7;
            half8 kv = *(const half8*)(Kg + (size_t)r * QKVROW + c * 8);
            *(half8*)(Ks + r * 128 + ((c ^ (r & 7)) << 4)) = kv;
        }
#pragma unroll
        for (int p = 0; p < 2; ++p) {
            const int f = tid + 256 * p;
            const int m = f >> 3, dc = f & 7;
            half8 vv = *(const half8*)(Vg + (size_t)m * QKVROW + dc * 8);
            const int mc = m >> 3, mo = m & 7;
#pragma unroll
            for (int j = 0; j < 8; ++j) {
                const int d = dc * 8 + j;
                *(_Float16*)(Vt + d * 128 + ((mc ^ (d & 7)) << 4) + mo * 2) = vv[j];
            }
        }
        // prefetch bias for this tile: iv[r][mi] = inter + mask additive (fp32)
        float iv[4][4];
#pragma unroll
        for (int r = 0; r < 4; ++r)
#pragma unroll
            for (int mi = 0; mi < 4; ++mi) {
                const int m = mt * 64 + mi * 16 + l15;
                const float bvv = interB[r][(size_t)m * CH];
                iv[r][mi] = bvv + (maskB[r][m] ? 0.f : -1e9f);
            }
        __syncthreads();

        // QK^T: S[16q x 64m] per wave
        f32x4 acc_s[4] = {};
#pragma unroll
        for (int step = 0; step < 2; ++step) {
            const int qrow = w * 16 + l15;
            const int ch = step * 4 + l4;
            half8 aq = *(const half8*)(Qs + qrow * 128 + ((ch ^ (qrow & 7)) << 4));
#pragma unroll
            for (int mi = 0; mi < 4; ++mi) {
                const int mrow = mi * 16 + l15;
                half8 bk = *(const half8*)(Ks + mrow * 128 + ((ch ^ (mrow & 7)) << 4));
                acc_s[mi] = __builtin_amdgcn_mfma_f32_16x16x32_f16(aq, bk, acc_s[mi], 0, 0, 0);
            }
        }
        // online softmax (row q = w*16 + l4*4 + r; col m = mi*16 + l15)
#pragma unroll
        for (int r = 0; r < 4; ++r) {
            float pv[4];
            float rmax = -3e38f;
#pragma unroll
            for (int mi = 0; mi < 4; ++mi) {
                float sv = acc_s[mi][r] * 0.125f + iv[r][mi];
                pv[mi] = sv;
                rmax = fmaxf(rmax, sv);
            }
#pragma unroll
            for (int off = 1; off < 16; off <<= 1) rmax = fmaxf(rmax, __shfl_xor(rmax, off));
            const float nm = fmaxf(m_run[r], rmax);
            const float fac = __expf(m_run[r] - nm);
            m_run[r] = nm;
            float ps = 0.f;
#pragma unroll
            for (int mi = 0; mi < 4; ++mi) { float e = __expf(pv[mi] - nm); pv[mi] = e; ps += e; }
#pragma unroll
            for (int off = 1; off < 16; off <<= 1) ps += __shfl_xor(ps, off);
            l_run[r] = l_run[r] * fac + ps;
#pragma unroll
            for (int di = 0; di < 4; ++di) acc_o[di][r] *= fac;
            const int qrow = w * 16 + l4 * 4 + r;
#pragma unroll
            for (int mi = 0; mi < 4; ++mi) {
                const int m = mi * 16 + l15;
                *(_Float16*)(Ps + qrow * 128 + (((m >> 3) ^ (qrow & 7)) << 4) + (m & 7) * 2) = (_Float16)pv[mi];
            }
        }
        // PV: O[16q x 64d] += P @ V  (Vt rows = d, k = m)
#pragma unroll
        for (int step = 0; step < 2; ++step) {
            const int qrow = w * 16 + l15;
            const int ch = step * 4 + l4;
            half8 ap = *(const half8*)(Ps + qrow * 128 + ((ch ^ (qrow & 7)) << 4));
#pragma unroll
            for (int di = 0; di < 4; ++di) {
                const int drow = di * 16 + l15;
                half8 bv = *(const half8*)(Vt + drow * 128 + ((ch ^ (drow & 7)) << 4));
                acc_o[di] = __builtin_amdgcn_mfma_f32_16x16x32_f16(ap, bv, acc_o[di], 0, 0, 0);
            }
        }
    }
    // epilogue
    _Float16* orow = o + (size_t)(b * CN + qt * 64 + w * 16 + l4 * 4) * CD + h * 64 + l15;
#pragma unroll
    for (int r = 0; r < 4; ++r) {
        const float inv = 1.0f / l_run[r];
#pragma unroll
        for (int di = 0; di < 4; ++di)
            orow[(size_t)r * CD + di * 16] = (_Float16)(acc_o[di][r] * inv);
    }
}

// ---------------- driver ----------------------------------------------------
extern "C" void kernel_launch(void* const* d_in, const int* in_sizes, int n_in,
                              void* d_out, int out_size, void* d_ws, size_t ws_size,
                              hipStream_t stream) {
    const float* x      = (const float*)d_in[0];
    const int*   mask   = (const int*)d_in[1];
    const float* inter  = (const float*)d_in[2];
    const float* w_qkv  = (const float*)d_in[3];
    const float* b_qkv  = (const float*)d_in[4];
    const float* w_out  = (const float*)d_in[5];
    const float* b_out  = (const float*)d_in[6];
    const float* w1     = (const float*)d_in[7];
    const float* b1     = (const float*)d_in[8];
    const float* w2     = (const float*)d_in[9];
    const float* b2     = (const float*)d_in[10];
    const float* g_pre  = (const float*)d_in[11];
    const float* be_pre = (const float*)d_in[12];
    const float* g_post = (const float*)d_in[13];
    const float* be_post= (const float*)d_in[14];
    const float* g_ffn  = (const float*)d_in[15];
    const float* be_ffn = (const float*)d_in[16];
    const float* g_mid  = (const float*)d_in[17];
    const float* be_mid = (const float*)d_in[18];
    float* out = (float*)d_out;

    char* ws = (char*)d_ws;
    const size_t MB = 1ull << 20;
    _Float16* wt_qkv = (_Float16*)(ws + 0 * MB);
    _Float16* wt_out = (_Float16*)(ws + 2 * MB);
    _Float16* wt_w1  = (_Float16*)(ws + 3 * MB);
    _Float16* wt_w2  = (_Float16*)(ws + 5 * MB);
    float*    attended = (float*)(ws + 8 * MB);       // [8,40) fp32
    _Float16* o2h    = (_Float16*)(ws + 40 * MB);     // [40,56) f16
    _Float16* f1b    = (_Float16*)(ws + 64 * MB);     // [64,128) f16 [M,2048]
    _Float16* qkvb   = (_Float16*)(ws + 128 * MB);    // [128,176)
    _Float16* hb     = (_Float16*)(ws + 176 * MB);    // [176,192)
    _Float16* ob     = (_Float16*)(ws + 192 * MB);    // [192,208)
    _Float16* fb     = (_Float16*)(ws + 208 * MB);    // [208,224)

    const int M = CB * CN;  // 16384

    // weight prep
    transpose_f16<<<dim3(1536 / 32, 512 / 32), 256, 0, stream>>>(w_qkv, wt_qkv, 512, 1536);
    transpose_f16<<<dim3(512 / 32, 512 / 32), 256, 0, stream>>>(w_out, wt_out, 512, 512);
    transpose_f16<<<dim3(2048 / 32, 512 / 32), 256, 0, stream>>>(w1, wt_w1, 512, 2048);
    transpose_f16<<<dim3(512 / 32, 2048 / 32), 256, 0, stream>>>(w2, wt_w2, 2048, 512);

    // 1. h = LN(x) -> f16
    ln2_kernel<512, false, true, false><<<M / 4, 256, 0, stream>>>(x, g_pre, be_pre, nullptr, hb);
    // 2. qkv = h @ w_qkv + b_qkv -> f16
    gemm_f16<false, false, true><<<(M / 128) * (1536 / 128), 256, 0, stream>>>(
        hb, wt_qkv, b_qkv, nullptr, qkvb, M, 1536, 512);
    // 3. attention (direct inter+mask) -> o f16
    attn_mfma<<<CB * 8 * 8, 256, 0, stream>>>(qkvb, inter, mask, ob);
    // 4. o2 = o @ w_out + b_out -> f16
    gemm_f16<false, false, true><<<(M / 128) * (512 / 128), 256, 0, stream>>>(
        ob, wt_out, b_out, nullptr, o2h, M, 512, 512);
    // 5+6. attended = LN(o2)+x (fp32); f = LN(attended) (f16)
    ln_post_ffn<<<M / 4, 256, 0, stream>>>(o2h, x, g_post, be_post, g_ffn, be_ffn, attended, fb);
    // 7. f1 = gelu(f @ w1 + b1) -> f16
    gemm_f16<true, false, true><<<(M / 128) * (2048 / 128), 256, 0, stream>>>(
        fb, wt_w1, b1, nullptr, f1b, M, 2048, 512);
    // 8. f1 = LN(f1) in-place
    ln2_kernel<2048, true, true, false><<<M / 4, 256, 0, stream>>>(f1b, g_mid, be_mid, nullptr, f1b);
    // 9. out = f1 @ w2 + b2 + attended -> fp32
    gemm_f16<false, true, false><<<(M / 128) * (512 / 128), 256, 0, stream>>>(
        f1b, wt_w2, b2, attended, out, M, 512, 2048);
}